// Round 12
// baseline (101.661 us; speedup 1.0000x reference)
//
#include <hip/hip_runtime.h>

#define TPB 256

typedef float f32x4 __attribute__((ext_vector_type(4)));

// lgkm-only barrier: orders LDS ops across the block without draining the
// global-store queue (HIP's __syncthreads emits s_waitcnt vmcnt(0)).
__device__ __forceinline__ void block_sync_lds() {
    asm volatile("s_waitcnt lgkmcnt(0)" ::: "memory");
    __builtin_amdgcn_s_barrier();
    asm volatile("" ::: "memory");
}

// Force a wave-uniform float into an SGPR.
__device__ __forceinline__ float sgpr(float x) {
    return __int_as_float(__builtin_amdgcn_readfirstlane(__float_as_int(x)));
}

// HBM -> LDS direct staging. LDS dest is wave-uniform base + lane*width;
// our layouts are linear so the constraint is satisfied.
__device__ __forceinline__ void gload_lds16(const float* g, float* l) {
    __builtin_amdgcn_global_load_lds(
        (const __attribute__((address_space(1))) void*)g,
        (__attribute__((address_space(3))) void*)l, 16, 0, 0);
}
__device__ __forceinline__ void gload_lds4(const float* g, float* l) {
    __builtin_amdgcn_global_load_lds(
        (const __attribute__((address_space(1))) void*)g,
        (__attribute__((address_space(3))) void*)l, 4, 0, 0);
}

// ---------------------------------------------------------------------------
// 3x3 QR (LAPACK Householder convention). M = Phi_P[level] row-major;
// P out = Phi[level] row-major (orthonormal rows).
// ---------------------------------------------------------------------------
__device__ __forceinline__ void qr3(const float* __restrict__ M, float* __restrict__ P) {
    float A[3][3];
#pragma unroll
    for (int r = 0; r < 3; ++r)
#pragma unroll
        for (int c = 0; c < 3; ++c)
            A[r][c] = M[c * 3 + r];  // A = Phi_P^T

    float V[3][3], tau[3];
#pragma unroll
    for (int k = 0; k < 3; ++k) {
        float alpha = A[k][k];
        float xn2 = 0.f;
#pragma unroll
        for (int r = k + 1; r < 3; ++r) xn2 += A[r][k] * A[r][k];
        float t = 0.f;
        float v[3] = {0.f, 0.f, 0.f};
        v[k] = 1.f;
        if (xn2 > 0.f) {
            float beta = -copysignf(sqrtf(alpha * alpha + xn2), alpha);
            t = (beta - alpha) / beta;
            float inv = 1.f / (alpha - beta);
#pragma unroll
            for (int r = k + 1; r < 3; ++r) v[r] = A[r][k] * inv;
#pragma unroll
            for (int c = 0; c < 3; ++c) {
                if (c < k) continue;
                float w = 0.f;
#pragma unroll
                for (int r = 0; r < 3; ++r) if (r >= k) w += v[r] * A[r][c];
                w *= t;
#pragma unroll
                for (int r = 0; r < 3; ++r) if (r >= k) A[r][c] -= w * v[r];
            }
        }
        tau[k] = t;
#pragma unroll
        for (int r = 0; r < 3; ++r) V[k][r] = v[r];
    }
    float Q[3][3] = {{1.f, 0.f, 0.f}, {0.f, 1.f, 0.f}, {0.f, 0.f, 1.f}};
#pragma unroll
    for (int k = 2; k >= 0; --k) {
#pragma unroll
        for (int c = 0; c < 3; ++c) {
            float w = 0.f;
#pragma unroll
            for (int r = 0; r < 3; ++r) w += V[k][r] * Q[r][c];
            w *= tau[k];
#pragma unroll
            for (int r = 0; r < 3; ++r) Q[r][c] -= w * V[k][r];
        }
    }
#pragma unroll
    for (int r = 0; r < 3; ++r)
#pragma unroll
        for (int c = 0; c < 3; ++c)
            P[r * 3 + c] = Q[c][r];  // Phi = Q^T
}

// K1 LDS staging origins (sections padded +8 for the alignment shift)
#define ORG_D1L0 0
#define ORG_D2L0 1160
#define ORG_D1L1 2320
#define ORG_D2L1 2712
#define ORG_D1L2 3104
#define ORG_D2L2 3240

// ---------------------------------------------------------------------------
// K1: fused levels 0-2 (unchanged from R10 — proven ~5.8 TB/s effective).
// ---------------------------------------------------------------------------
__global__ __launch_bounds__(TPB, 8) void fused3_kernel(
        const float* __restrict__ in, float* __restrict__ out,
        float* __restrict__ avg_out, const float* __restrict__ PhiP,
        int lvl, int m2) {
    __shared__ float s[3456];
    const int  t = threadIdx.x;
    const long b = blockIdx.x;
    const long nF = 27L * m2;
    const long fBase = 3456L * b;
    const long M0 = 9L * m2, M1 = 3L * m2, M2 = m2;

    const bool full = (128L * (b + 1) <= (long)m2);

    const long A0 = M0 + 1152L * b;
    const long A1 = 2 * M0 + 1152L * b;
    const long A2 = M1 + 384L * b;
    const long A3 = 2 * M1 + 384L * b;
    const long A4 = M2 + 128L * b;
    const long A5 = 2 * M2 + 128L * b;
    const int o0 = (int)(A0 & 3), o1 = (int)(A1 & 3), o2 = (int)(A2 & 3);
    const int o3 = (int)(A3 & 3), o4 = (int)(A4 & 3), o5 = (int)(A5 & 3);

    // ---- Phase A: direct HBM->LDS staging (round 4 re-covers the tail)
    if (full) {
        const float* src = in + fBase;
#pragma unroll
        for (int r = 0; r < 3; ++r) {
            int c = 256 * r + t;
            gload_lds16(src + 4 * c, &s[4 * c]);
        }
        {
            int c = 608 + t;  // overlaps round 2 by 160 (same data, benign)
            gload_lds16(src + 4 * c, &s[4 * c]);
        }
    } else {
        const long rem = nF - fBase;
        for (int i = t; i < 3456; i += TPB) s[i] = (i < rem) ? in[fBase + i] : 0.f;
    }

    // ---- QR (overlaps staging latency)
    float P[27];
    qr3(PhiP + 9L * lvl,       P + 0);
    qr3(PhiP + 9L * (lvl + 1), P + 9);
    qr3(PhiP + 9L * (lvl + 2), P + 18);
#pragma unroll
    for (int j = 0; j < 27; ++j) P[j] = sgpr(P[j]);

    __syncthreads();  // drains the global_load_lds queue + barrier

    // ---- Phase B: transpose read (threads 0-127 own 27 consecutive floats)
    float f[27];
    const bool act = (t < 128);
    if (act) {
#pragma unroll
        for (int j = 0; j < 27; ++j) f[j] = s[27 * t + j];
    }
    block_sync_lds();  // all reads done before s is overwritten

    // ---- Phase C: compute, stage details (shifted)
    float c;
    if (act) {
        float a[9];
#pragma unroll
        for (int g = 0; g < 9; ++g) {
            float x = f[3 * g], y = f[3 * g + 1], z = f[3 * g + 2];
            a[g] = x * P[0] + y * P[1] + z * P[2];
            s[ORG_D1L0 + o0 + 9 * t + g] = x * P[3] + y * P[4] + z * P[5];
            s[ORG_D2L0 + o1 + 9 * t + g] = x * P[6] + y * P[7] + z * P[8];
        }
        float bb[3];
#pragma unroll
        for (int h = 0; h < 3; ++h) {
            float x = a[3 * h], y = a[3 * h + 1], z = a[3 * h + 2];
            bb[h] = x * P[9] + y * P[10] + z * P[11];
            s[ORG_D1L1 + o2 + 3 * t + h] = x * P[12] + y * P[13] + z * P[14];
            s[ORG_D2L1 + o3 + 3 * t + h] = x * P[15] + y * P[16] + z * P[17];
        }
        float x = bb[0], y = bb[1], z = bb[2];
        c = x * P[18] + y * P[19] + z * P[20];
        s[ORG_D1L2 + o4 + t] = x * P[21] + y * P[22] + z * P[23];
        s[ORG_D2L2 + o5 + t] = x * P[24] + y * P[25] + z * P[26];
    }
    block_sync_lds();

    // ---- Phase D: nontemporal f32x4 store rounds (queue, never wait)
#define STORE_SEC(ORG, A, O, CNT, ROUNDS)                                      \
    {                                                                          \
        float* dst = out + (A);                                                \
        const int aH = (4 - (O)) & 3;                                          \
        const int nb = ((CNT) - aH) >> 2;                                      \
        const int tl = (CNT) - aH - 4 * nb;                                    \
        if (t < aH) __builtin_nontemporal_store(s[(ORG) + (O) + t], dst + t);  \
        _Pragma("unroll")                                                      \
        for (int r = 0; r < (ROUNDS); ++r) {                                   \
            int idx = 256 * r + t;                                             \
            if (idx < nb) {                                                    \
                f32x4 vv = *reinterpret_cast<const f32x4*>(                    \
                    &s[(ORG) + (O) + aH + 4 * idx]);                           \
                __builtin_nontemporal_store(                                   \
                    vv, reinterpret_cast<f32x4*>(dst + aH) + idx);             \
            }                                                                  \
        }                                                                      \
        if (t < tl)                                                            \
            __builtin_nontemporal_store(s[(ORG) + (O) + aH + 4 * nb + t],      \
                                        dst + aH + 4 * nb + t);                \
    }

    if (full) {
        STORE_SEC(ORG_D1L0, A0, o0, 1152, 2);
        STORE_SEC(ORG_D2L0, A1, o1, 1152, 2);
        STORE_SEC(ORG_D1L1, A2, o2, 384, 1);
        STORE_SEC(ORG_D2L1, A3, o3, 384, 1);
        STORE_SEC(ORG_D1L2, A4, o4, 128, 1);
        STORE_SEC(ORG_D2L2, A5, o5, 128, 1);
        if (act) avg_out[128L * b + t] = c;
    } else {
#pragma unroll
        for (int r = 0; r < 5; ++r) {
            int i = 256 * r + t;
            long g = 1152L * b + i;
            if (i < 1152 && g < M0) {
                __builtin_nontemporal_store(s[ORG_D1L0 + o0 + i], out + M0 + g);
                __builtin_nontemporal_store(s[ORG_D2L0 + o1 + i], out + 2 * M0 + g);
            }
        }
#pragma unroll
        for (int r = 0; r < 2; ++r) {
            int i = 256 * r + t;
            long g = 384L * b + i;
            if (i < 384 && g < M1) {
                __builtin_nontemporal_store(s[ORG_D1L1 + o2 + i], out + M1 + g);
                __builtin_nontemporal_store(s[ORG_D2L1 + o3 + i], out + 2 * M1 + g);
            }
        }
        long g = 128L * b + t;
        if (act && g < M2) {
            __builtin_nontemporal_store(s[ORG_D1L2 + o4 + t], out + M2 + g);
            __builtin_nontemporal_store(s[ORG_D2L2 + o5 + t], out + 2 * M2 + g);
            avg_out[g] = c;
        }
    }
#undef STORE_SEC
}

// ---------------------------------------------------------------------------
// K2: fused levels 3-8 + inline tail (levels 9-15) via last-block handshake.
// sPhi layout: level L at sPhi[(L-3)*9] — tail level 9 starts at sPhi[54].
// ---------------------------------------------------------------------------
__global__ __launch_bounds__(TPB) void mid_kernel(
        const float* __restrict__ in, float* __restrict__ out,
        float* __restrict__ bufC, const float* __restrict__ PhiP,
        int* __restrict__ cnt) {
    __shared__ float s[6912];
    __shared__ float sc[243];
    __shared__ float sc2[81];
    __shared__ float sc3[27];
    __shared__ float sPhi[117];
    __shared__ int sLast;
    const int  t = threadIdx.x;
    const long b = blockIdx.x;
    const float* src = in + 6561L * b;

#pragma unroll
    for (int r = 0; r < 26; ++r) {
        int i = 256 * r + t;
        gload_lds4(src + i, &s[i]);
    }
    // QR for levels 3..15, one per lane (overlaps staging)
    if (t < 13) {
        float P[9];
        qr3(PhiP + 9L * (3 + t), P);
#pragma unroll
        for (int j = 0; j < 9; ++j) sPhi[9 * t + j] = P[j];
    }
    __syncthreads();

    float P[27];
#pragma unroll
    for (int j = 0; j < 27; ++j) P[j] = sgpr(sPhi[j]);

    float f27[27];
    const bool act = (t < 243);
    if (act) {
#pragma unroll
        for (int j = 0; j < 27; ++j) f27[j] = s[27 * t + j];
    }
    block_sync_lds();

    if (act) {
        float a[9];
#pragma unroll
        for (int g = 0; g < 9; ++g) {
            float x = f27[3 * g], y = f27[3 * g + 1], z = f27[3 * g + 2];
            a[g] = x * P[0] + y * P[1] + z * P[2];
            s[9 * t + g]        = x * P[3] + y * P[4] + z * P[5];
            s[2187 + 9 * t + g] = x * P[6] + y * P[7] + z * P[8];
        }
        float bb[3];
#pragma unroll
        for (int h = 0; h < 3; ++h) {
            float x = a[3 * h], y = a[3 * h + 1], z = a[3 * h + 2];
            bb[h] = x * P[9] + y * P[10] + z * P[11];
            s[4374 + 3 * t + h] = x * P[12] + y * P[13] + z * P[14];
            s[5103 + 3 * t + h] = x * P[15] + y * P[16] + z * P[17];
        }
        float x = bb[0], y = bb[1], z = bb[2];
        sc[t]        = x * P[18] + y * P[19] + z * P[20];
        s[5832 + t]  = x * P[21] + y * P[22] + z * P[23];
        s[6075 + t]  = x * P[24] + y * P[25] + z * P[26];
    }
    block_sync_lds();

    if (t < 81) {
        float x = sc[3 * t], y = sc[3 * t + 1], z = sc[3 * t + 2];
        sc2[t]      = x * sPhi[27] + y * sPhi[28] + z * sPhi[29];
        s[6318 + t] = x * sPhi[30] + y * sPhi[31] + z * sPhi[32];
        s[6399 + t] = x * sPhi[33] + y * sPhi[34] + z * sPhi[35];
    }
    block_sync_lds();
    if (t < 27) {
        float x = sc2[3 * t], y = sc2[3 * t + 1], z = sc2[3 * t + 2];
        sc3[t]      = x * sPhi[36] + y * sPhi[37] + z * sPhi[38];
        s[6480 + t] = x * sPhi[39] + y * sPhi[40] + z * sPhi[41];
        s[6507 + t] = x * sPhi[42] + y * sPhi[43] + z * sPhi[44];
    }
    block_sync_lds();
    if (t < 9) {
        float x = sc3[3 * t], y = sc3[3 * t + 1], z = sc3[3 * t + 2];
        bufC[9 * b + t] = x * sPhi[45] + y * sPhi[46] + z * sPhi[47];
        s[6534 + t] = x * sPhi[48] + y * sPhi[49] + z * sPhi[50];
        s[6543 + t] = x * sPhi[51] + y * sPhi[52] + z * sPhi[53];
    }
    block_sync_lds();

    // ---- detail stores (nt)
    const long B0 = 2187L * b, B1 = 729L * b, B2 = 243L * b;
    const long B3 = 81L * b, B4 = 27L * b, B5 = 9L * b;
#pragma unroll
    for (int r = 0; r < 9; ++r) {
        int i = 256 * r + t;
        if (i < 2187) {
            __builtin_nontemporal_store(s[i],        out + 531441 + B0 + i);
            __builtin_nontemporal_store(s[2187 + i], out + 2 * 531441 + B0 + i);
        }
    }
#pragma unroll
    for (int r = 0; r < 3; ++r) {
        int i = 256 * r + t;
        if (i < 729) {
            __builtin_nontemporal_store(s[4374 + i], out + 177147 + B1 + i);
            __builtin_nontemporal_store(s[5103 + i], out + 2 * 177147 + B1 + i);
        }
    }
    if (t < 243) {
        __builtin_nontemporal_store(s[5832 + t], out + 59049 + B2 + t);
        __builtin_nontemporal_store(s[6075 + t], out + 2 * 59049 + B2 + t);
    }
    if (t < 81) {
        __builtin_nontemporal_store(s[6318 + t], out + 19683 + B3 + t);
        __builtin_nontemporal_store(s[6399 + t], out + 2 * 19683 + B3 + t);
    }
    if (t < 27) {
        __builtin_nontemporal_store(s[6480 + t], out + 6561 + B4 + t);
        __builtin_nontemporal_store(s[6507 + t], out + 2 * 6561 + B4 + t);
    }
    if (t < 9) {
        __builtin_nontemporal_store(s[6534 + t], out + 2187 + B5 + t);
        __builtin_nontemporal_store(s[6543 + t], out + 2 * 2187 + B5 + t);
    }

    // ---- handshake: release this block's bufC writes, count arrivals
    __threadfence();      // device-scope release (bufC stores by t<9)
    __syncthreads();      // order t0's atomic after all threads' fences
    if (t == 0) {
        int old = __hip_atomic_fetch_add(cnt, 1, __ATOMIC_ACQ_REL,
                                         __HIP_MEMORY_SCOPE_AGENT);
        sLast = (old == 242);
    }
    __syncthreads();
    if (!sLast) return;

    // ---- last block: tail levels 9-15 on bufC (2187 floats)
    __threadfence();      // acquire: other blocks' bufC writes visible
    block_sync_lds();     // s[] LDS reads from store phase complete
    for (int i = t; i < 2187; i += TPB) s[i] = bufC[i];
    block_sync_lds();

    float* cur = s;
    float* nxt = s + 2187;
    int len = 2187;
#pragma unroll
    for (int L = 0; L < 7; ++L) {
        int m = len / 3;
        float p0 = sPhi[54 + L * 9 + 0], p1 = sPhi[54 + L * 9 + 1], p2 = sPhi[54 + L * 9 + 2];
        float q0 = sPhi[54 + L * 9 + 3], q1 = sPhi[54 + L * 9 + 4], q2 = sPhi[54 + L * 9 + 5];
        float r0 = sPhi[54 + L * 9 + 6], r1 = sPhi[54 + L * 9 + 7], r2 = sPhi[54 + L * 9 + 8];
        for (int u = t; u < m; u += TPB) {
            float x = cur[3 * u], y = cur[3 * u + 1], z = cur[3 * u + 2];
            out[m + u]     = x * q0 + y * q1 + z * q2;
            out[2 * m + u] = x * r0 + y * r1 + z * r2;
            nxt[u]         = x * p0 + y * p1 + z * p2;
        }
        block_sync_lds();
        float* tmp = cur; cur = nxt; nxt = tmp;
        len = m;
    }
    if (t == 0) out[0] = cur[0];
}

extern "C" void kernel_launch(void* const* d_in, const int* in_sizes, int n_in,
                              void* d_out, int out_size, void* d_ws, size_t ws_size,
                              hipStream_t stream) {
    const float* f    = (const float*)d_in[0];   // 3^16 floats
    const float* PhiP = (const float*)d_in[1];   // 16*3*3 floats
    float* out = (float*)d_out;                  // 3^16 floats
    float* ws  = (float*)d_ws;

    float* bufA = ws;                // 3^13 floats (avg after levels 0-2)
    float* bufC = bufA + 1594323;    // 2187 floats (avg after levels 3-8)
    int*   cnt  = (int*)(bufC + 2188);  // arrival counter (4B, aligned)

    hipMemsetAsync(cnt, 0, sizeof(int), stream);  // capture-safe

    const int m2_0 = 1594323;  // 3^13, levels 0-2
    const int grid1 = (m2_0 + 127) / 128;  // 12456 blocks
    fused3_kernel<<<grid1, TPB, 0, stream>>>(f, out, bufA, PhiP, 0, m2_0);

    mid_kernel<<<243, TPB, 0, stream>>>(bufA, out, bufC, PhiP, cnt);  // levels 3-15
}

// Round 13
// 69.442 us; speedup vs baseline: 1.4640x; 1.4640x over previous
//
#include <hip/hip_runtime.h>

#define TPB 256

typedef float f32x4 __attribute__((ext_vector_type(4)));

// lgkm-only barrier: orders LDS ops across the block without draining the
// global-store queue (HIP's __syncthreads emits s_waitcnt vmcnt(0)).
__device__ __forceinline__ void block_sync_lds() {
    asm volatile("s_waitcnt lgkmcnt(0)" ::: "memory");
    __builtin_amdgcn_s_barrier();
    asm volatile("" ::: "memory");
}

// Force a wave-uniform float into an SGPR.
__device__ __forceinline__ float sgpr(float x) {
    return __int_as_float(__builtin_amdgcn_readfirstlane(__float_as_int(x)));
}

// HBM -> LDS direct staging. LDS dest is wave-uniform base + lane*width;
// our layouts are linear so the constraint is satisfied.
__device__ __forceinline__ void gload_lds16(const float* g, float* l) {
    __builtin_amdgcn_global_load_lds(
        (const __attribute__((address_space(1))) void*)g,
        (__attribute__((address_space(3))) void*)l, 16, 0, 0);
}
__device__ __forceinline__ void gload_lds4(const float* g, float* l) {
    __builtin_amdgcn_global_load_lds(
        (const __attribute__((address_space(1))) void*)g,
        (__attribute__((address_space(3))) void*)l, 4, 0, 0);
}

// ---------------------------------------------------------------------------
// 3x3 QR (LAPACK Householder convention). M = Phi_P[level] row-major;
// P out = Phi[level] row-major (orthonormal rows).
// ---------------------------------------------------------------------------
__device__ __forceinline__ void qr3(const float* __restrict__ M, float* __restrict__ P) {
    float A[3][3];
#pragma unroll
    for (int r = 0; r < 3; ++r)
#pragma unroll
        for (int c = 0; c < 3; ++c)
            A[r][c] = M[c * 3 + r];  // A = Phi_P^T

    float V[3][3], tau[3];
#pragma unroll
    for (int k = 0; k < 3; ++k) {
        float alpha = A[k][k];
        float xn2 = 0.f;
#pragma unroll
        for (int r = k + 1; r < 3; ++r) xn2 += A[r][k] * A[r][k];
        float t = 0.f;
        float v[3] = {0.f, 0.f, 0.f};
        v[k] = 1.f;
        if (xn2 > 0.f) {
            float beta = -copysignf(sqrtf(alpha * alpha + xn2), alpha);
            t = (beta - alpha) / beta;
            float inv = 1.f / (alpha - beta);
#pragma unroll
            for (int r = k + 1; r < 3; ++r) v[r] = A[r][k] * inv;
#pragma unroll
            for (int c = 0; c < 3; ++c) {
                if (c < k) continue;
                float w = 0.f;
#pragma unroll
                for (int r = 0; r < 3; ++r) if (r >= k) w += v[r] * A[r][c];
                w *= t;
#pragma unroll
                for (int r = 0; r < 3; ++r) if (r >= k) A[r][c] -= w * v[r];
            }
        }
        tau[k] = t;
#pragma unroll
        for (int r = 0; r < 3; ++r) V[k][r] = v[r];
    }
    float Q[3][3] = {{1.f, 0.f, 0.f}, {0.f, 1.f, 0.f}, {0.f, 0.f, 1.f}};
#pragma unroll
    for (int k = 2; k >= 0; --k) {
#pragma unroll
        for (int c = 0; c < 3; ++c) {
            float w = 0.f;
#pragma unroll
            for (int r = 0; r < 3; ++r) w += V[k][r] * Q[r][c];
            w *= tau[k];
#pragma unroll
            for (int r = 0; r < 3; ++r) Q[r][c] -= w * V[k][r];
        }
    }
#pragma unroll
    for (int r = 0; r < 3; ++r)
#pragma unroll
        for (int c = 0; c < 3; ++c)
            P[r * 3 + c] = Q[c][r];  // Phi = Q^T
}

// K1 LDS staging origins (sections padded +8 for the alignment shift)
#define ORG_D1L0 0
#define ORG_D2L0 1160
#define ORG_D1L1 2320
#define ORG_D2L1 2712
#define ORG_D1L2 3104
#define ORG_D2L2 3240

// ---------------------------------------------------------------------------
// K1: fused levels 0-2 (R10-proven: ~5.8 TB/s effective, 8 blocks/CU).
// ---------------------------------------------------------------------------
__global__ __launch_bounds__(TPB, 8) void fused3_kernel(
        const float* __restrict__ in, float* __restrict__ out,
        float* __restrict__ avg_out, const float* __restrict__ PhiP,
        int lvl, int m2) {
    __shared__ float s[3456];
    const int  t = threadIdx.x;
    const long b = blockIdx.x;
    const long nF = 27L * m2;
    const long fBase = 3456L * b;
    const long M0 = 9L * m2, M1 = 3L * m2, M2 = m2;

    const bool full = (128L * (b + 1) <= (long)m2);

    const long A0 = M0 + 1152L * b;
    const long A1 = 2 * M0 + 1152L * b;
    const long A2 = M1 + 384L * b;
    const long A3 = 2 * M1 + 384L * b;
    const long A4 = M2 + 128L * b;
    const long A5 = 2 * M2 + 128L * b;
    const int o0 = (int)(A0 & 3), o1 = (int)(A1 & 3), o2 = (int)(A2 & 3);
    const int o3 = (int)(A3 & 3), o4 = (int)(A4 & 3), o5 = (int)(A5 & 3);

    // ---- Phase A: direct HBM->LDS staging (round 4 re-covers the tail)
    if (full) {
        const float* src = in + fBase;
#pragma unroll
        for (int r = 0; r < 3; ++r) {
            int c = 256 * r + t;
            gload_lds16(src + 4 * c, &s[4 * c]);
        }
        {
            int c = 608 + t;  // overlaps round 2 by 160 (same data, benign)
            gload_lds16(src + 4 * c, &s[4 * c]);
        }
    } else {
        const long rem = nF - fBase;
        for (int i = t; i < 3456; i += TPB) s[i] = (i < rem) ? in[fBase + i] : 0.f;
    }

    // ---- QR (overlaps staging latency)
    float P[27];
    qr3(PhiP + 9L * lvl,       P + 0);
    qr3(PhiP + 9L * (lvl + 1), P + 9);
    qr3(PhiP + 9L * (lvl + 2), P + 18);
#pragma unroll
    for (int j = 0; j < 27; ++j) P[j] = sgpr(P[j]);

    __syncthreads();  // drains the global_load_lds queue + barrier

    // ---- Phase B: transpose read (threads 0-127 own 27 consecutive floats)
    float f[27];
    const bool act = (t < 128);
    if (act) {
#pragma unroll
        for (int j = 0; j < 27; ++j) f[j] = s[27 * t + j];
    }
    block_sync_lds();  // all reads done before s is overwritten

    // ---- Phase C: compute, stage details (shifted)
    float c;
    if (act) {
        float a[9];
#pragma unroll
        for (int g = 0; g < 9; ++g) {
            float x = f[3 * g], y = f[3 * g + 1], z = f[3 * g + 2];
            a[g] = x * P[0] + y * P[1] + z * P[2];
            s[ORG_D1L0 + o0 + 9 * t + g] = x * P[3] + y * P[4] + z * P[5];
            s[ORG_D2L0 + o1 + 9 * t + g] = x * P[6] + y * P[7] + z * P[8];
        }
        float bb[3];
#pragma unroll
        for (int h = 0; h < 3; ++h) {
            float x = a[3 * h], y = a[3 * h + 1], z = a[3 * h + 2];
            bb[h] = x * P[9] + y * P[10] + z * P[11];
            s[ORG_D1L1 + o2 + 3 * t + h] = x * P[12] + y * P[13] + z * P[14];
            s[ORG_D2L1 + o3 + 3 * t + h] = x * P[15] + y * P[16] + z * P[17];
        }
        float x = bb[0], y = bb[1], z = bb[2];
        c = x * P[18] + y * P[19] + z * P[20];
        s[ORG_D1L2 + o4 + t] = x * P[21] + y * P[22] + z * P[23];
        s[ORG_D2L2 + o5 + t] = x * P[24] + y * P[25] + z * P[26];
    }
    block_sync_lds();

    // ---- Phase D: nontemporal f32x4 store rounds (queue, never wait)
#define STORE_SEC(ORG, A, O, CNT, ROUNDS)                                      \
    {                                                                          \
        float* dst = out + (A);                                                \
        const int aH = (4 - (O)) & 3;                                          \
        const int nb = ((CNT) - aH) >> 2;                                      \
        const int tl = (CNT) - aH - 4 * nb;                                    \
        if (t < aH) __builtin_nontemporal_store(s[(ORG) + (O) + t], dst + t);  \
        _Pragma("unroll")                                                      \
        for (int r = 0; r < (ROUNDS); ++r) {                                   \
            int idx = 256 * r + t;                                             \
            if (idx < nb) {                                                    \
                f32x4 vv = *reinterpret_cast<const f32x4*>(                    \
                    &s[(ORG) + (O) + aH + 4 * idx]);                           \
                __builtin_nontemporal_store(                                   \
                    vv, reinterpret_cast<f32x4*>(dst + aH) + idx);             \
            }                                                                  \
        }                                                                      \
        if (t < tl)                                                            \
            __builtin_nontemporal_store(s[(ORG) + (O) + aH + 4 * nb + t],      \
                                        dst + aH + 4 * nb + t);                \
    }

    if (full) {
        STORE_SEC(ORG_D1L0, A0, o0, 1152, 2);
        STORE_SEC(ORG_D2L0, A1, o1, 1152, 2);
        STORE_SEC(ORG_D1L1, A2, o2, 384, 1);
        STORE_SEC(ORG_D2L1, A3, o3, 384, 1);
        STORE_SEC(ORG_D1L2, A4, o4, 128, 1);
        STORE_SEC(ORG_D2L2, A5, o5, 128, 1);
        if (act) avg_out[128L * b + t] = c;
    } else {
#pragma unroll
        for (int r = 0; r < 5; ++r) {
            int i = 256 * r + t;
            long g = 1152L * b + i;
            if (i < 1152 && g < M0) {
                __builtin_nontemporal_store(s[ORG_D1L0 + o0 + i], out + M0 + g);
                __builtin_nontemporal_store(s[ORG_D2L0 + o1 + i], out + 2 * M0 + g);
            }
        }
#pragma unroll
        for (int r = 0; r < 2; ++r) {
            int i = 256 * r + t;
            long g = 384L * b + i;
            if (i < 384 && g < M1) {
                __builtin_nontemporal_store(s[ORG_D1L1 + o2 + i], out + M1 + g);
                __builtin_nontemporal_store(s[ORG_D2L1 + o3 + i], out + 2 * M1 + g);
            }
        }
        long g = 128L * b + t;
        if (act && g < M2) {
            __builtin_nontemporal_store(s[ORG_D1L2 + o4 + t], out + M2 + g);
            __builtin_nontemporal_store(s[ORG_D2L2 + o5 + t], out + 2 * M2 + g);
            avg_out[g] = c;
        }
    }
#undef STORE_SEC
}

// ---------------------------------------------------------------------------
// K2: fused levels 3-8 (R10-proven). 243 blocks x 256 threads.
// ---------------------------------------------------------------------------
__global__ __launch_bounds__(TPB) void mid_kernel(
        const float* __restrict__ in, float* __restrict__ out,
        float* __restrict__ avg_out, const float* __restrict__ PhiP) {
    __shared__ float s[6912];
    __shared__ float sc[243];
    __shared__ float sc2[81];
    __shared__ float sc3[27];
    __shared__ float sPhi[54];
    const int  t = threadIdx.x;
    const long b = blockIdx.x;
    const float* src = in + 6561L * b;

#pragma unroll
    for (int r = 0; r < 26; ++r) {
        int i = 256 * r + t;
        gload_lds4(src + i, &s[i]);
    }
    if (t < 6) {
        float P[9];
        qr3(PhiP + 9L * (3 + t), P);
#pragma unroll
        for (int j = 0; j < 9; ++j) sPhi[9 * t + j] = P[j];
    }
    __syncthreads();

    float P[27];
#pragma unroll
    for (int j = 0; j < 27; ++j) P[j] = sgpr(sPhi[j]);

    float f27[27];
    const bool act = (t < 243);
    if (act) {
#pragma unroll
        for (int j = 0; j < 27; ++j) f27[j] = s[27 * t + j];
    }
    block_sync_lds();

    if (act) {
        float a[9];
#pragma unroll
        for (int g = 0; g < 9; ++g) {
            float x = f27[3 * g], y = f27[3 * g + 1], z = f27[3 * g + 2];
            a[g] = x * P[0] + y * P[1] + z * P[2];
            s[9 * t + g]        = x * P[3] + y * P[4] + z * P[5];
            s[2187 + 9 * t + g] = x * P[6] + y * P[7] + z * P[8];
        }
        float bb[3];
#pragma unroll
        for (int h = 0; h < 3; ++h) {
            float x = a[3 * h], y = a[3 * h + 1], z = a[3 * h + 2];
            bb[h] = x * P[9] + y * P[10] + z * P[11];
            s[4374 + 3 * t + h] = x * P[12] + y * P[13] + z * P[14];
            s[5103 + 3 * t + h] = x * P[15] + y * P[16] + z * P[17];
        }
        float x = bb[0], y = bb[1], z = bb[2];
        sc[t]        = x * P[18] + y * P[19] + z * P[20];
        s[5832 + t]  = x * P[21] + y * P[22] + z * P[23];
        s[6075 + t]  = x * P[24] + y * P[25] + z * P[26];
    }
    block_sync_lds();

    if (t < 81) {
        float x = sc[3 * t], y = sc[3 * t + 1], z = sc[3 * t + 2];
        sc2[t]      = x * sPhi[27] + y * sPhi[28] + z * sPhi[29];
        s[6318 + t] = x * sPhi[30] + y * sPhi[31] + z * sPhi[32];
        s[6399 + t] = x * sPhi[33] + y * sPhi[34] + z * sPhi[35];
    }
    block_sync_lds();
    if (t < 27) {
        float x = sc2[3 * t], y = sc2[3 * t + 1], z = sc2[3 * t + 2];
        sc3[t]      = x * sPhi[36] + y * sPhi[37] + z * sPhi[38];
        s[6480 + t] = x * sPhi[39] + y * sPhi[40] + z * sPhi[41];
        s[6507 + t] = x * sPhi[42] + y * sPhi[43] + z * sPhi[44];
    }
    block_sync_lds();
    if (t < 9) {
        float x = sc3[3 * t], y = sc3[3 * t + 1], z = sc3[3 * t + 2];
        avg_out[9 * b + t] = x * sPhi[45] + y * sPhi[46] + z * sPhi[47];
        s[6534 + t] = x * sPhi[48] + y * sPhi[49] + z * sPhi[50];
        s[6543 + t] = x * sPhi[51] + y * sPhi[52] + z * sPhi[53];
    }
    block_sync_lds();

    const long B0 = 2187L * b, B1 = 729L * b, B2 = 243L * b;
    const long B3 = 81L * b, B4 = 27L * b, B5 = 9L * b;
#pragma unroll
    for (int r = 0; r < 9; ++r) {
        int i = 256 * r + t;
        if (i < 2187) {
            __builtin_nontemporal_store(s[i],        out + 531441 + B0 + i);
            __builtin_nontemporal_store(s[2187 + i], out + 2 * 531441 + B0 + i);
        }
    }
#pragma unroll
    for (int r = 0; r < 3; ++r) {
        int i = 256 * r + t;
        if (i < 729) {
            __builtin_nontemporal_store(s[4374 + i], out + 177147 + B1 + i);
            __builtin_nontemporal_store(s[5103 + i], out + 2 * 177147 + B1 + i);
        }
    }
    if (t < 243) {
        __builtin_nontemporal_store(s[5832 + t], out + 59049 + B2 + t);
        __builtin_nontemporal_store(s[6075 + t], out + 2 * 59049 + B2 + t);
    }
    if (t < 81) {
        __builtin_nontemporal_store(s[6318 + t], out + 19683 + B3 + t);
        __builtin_nontemporal_store(s[6399 + t], out + 2 * 19683 + B3 + t);
    }
    if (t < 27) {
        __builtin_nontemporal_store(s[6480 + t], out + 6561 + B4 + t);
        __builtin_nontemporal_store(s[6507 + t], out + 2 * 6561 + B4 + t);
    }
    if (t < 9) {
        __builtin_nontemporal_store(s[6534 + t], out + 2187 + B5 + t);
        __builtin_nontemporal_store(s[6543 + t], out + 2 * 2187 + B5 + t);
    }
}

// ---------------------------------------------------------------------------
// Tail: levels 9..15, one block of 1024 threads, LDS ping-pong (input 2187).
// ---------------------------------------------------------------------------
#define TTPB 1024
__global__ __launch_bounds__(TTPB) void tail_kernel(
        const float* __restrict__ in, float* __restrict__ out,
        const float* __restrict__ PhiP) {
    __shared__ float s0[2187];
    __shared__ float s1[729];
    __shared__ float sPhi[63];
    const int lt = threadIdx.x;

    for (int i = lt; i < 2187; i += TTPB) s0[i] = in[i];
    if (lt < 7) {
        float P[9];
        qr3(PhiP + 9L * (9 + lt), P);
#pragma unroll
        for (int j = 0; j < 9; ++j) sPhi[lt * 9 + j] = P[j];
    }
    __syncthreads();

    float* cur = s0;
    float* nxt = s1;
    int len = 2187;
#pragma unroll
    for (int L = 0; L < 7; ++L) {
        int m = len / 3;
        float p0 = sPhi[L * 9 + 0], p1 = sPhi[L * 9 + 1], p2 = sPhi[L * 9 + 2];
        float q0 = sPhi[L * 9 + 3], q1 = sPhi[L * 9 + 4], q2 = sPhi[L * 9 + 5];
        float r0 = sPhi[L * 9 + 6], r1 = sPhi[L * 9 + 7], r2 = sPhi[L * 9 + 8];
        for (int t = lt; t < m; t += TTPB) {
            float x = cur[3 * t], y = cur[3 * t + 1], z = cur[3 * t + 2];
            out[m + t]     = x * q0 + y * q1 + z * q2;
            out[2 * m + t] = x * r0 + y * r1 + z * r2;
            nxt[t]         = x * p0 + y * p1 + z * p2;
        }
        block_sync_lds();
        float* tmp = cur; cur = nxt; nxt = tmp;
        len = m;
    }
    if (lt == 0) out[0] = cur[0];
}

extern "C" void kernel_launch(void* const* d_in, const int* in_sizes, int n_in,
                              void* d_out, int out_size, void* d_ws, size_t ws_size,
                              hipStream_t stream) {
    const float* f    = (const float*)d_in[0];   // 3^16 floats
    const float* PhiP = (const float*)d_in[1];   // 16*3*3 floats
    float* out = (float*)d_out;                  // 3^16 floats
    float* ws  = (float*)d_ws;

    float* bufA = ws;                // 3^13 floats (avg after levels 0-2)
    float* bufC = bufA + 1594323;    // 2187 floats (avg after levels 3-8)

    const int m2_0 = 1594323;  // 3^13, levels 0-2
    const int grid1 = (m2_0 + 127) / 128;  // 12456 blocks
    fused3_kernel<<<grid1, TPB, 0, stream>>>(f, out, bufA, PhiP, 0, m2_0);

    mid_kernel<<<243, TPB, 0, stream>>>(bufA, out, bufC, PhiP);  // levels 3-8

    tail_kernel<<<1, TTPB, 0, stream>>>(bufC, out, PhiP);        // levels 9-15
}